// Round 1
// baseline (682.305 us; speedup 1.0000x reference)
//
#include <hip/hip_runtime.h>
#include <math.h>

// Problem constants
#define BB 8
#define SS 1024
#define DMM 512
#define HH 8
#define DKK 32
#define DHH 64
// M = BB*SS = 8192

// ---------------------------------------------------------------------------
// Generic tiled GEMM: C[M,N] = A[M,512] @ W[N,512]^T  (+ epilogue per MODE)
// MODE 0: QKV projection, W split across Wq(256)/Wk(256)/Wv(512) regions, N=1024
// MODE 1: C = A@Wo^T + bias + resid               (N=512)
// MODE 2: C = resid + leaky_relu(A@Wf^T + bias)   (N=512)
// Tile 64x64, BK=32, 256 threads, 4x4 per thread.
// LDS layout [k][row] (pad 68) so inner loop reads are two ds_read_b128.
// ---------------------------------------------------------------------------
template <int MODE>
__global__ __launch_bounds__(256) void gemm_xwt(
    const float* __restrict__ A, const float* __restrict__ W0,
    const float* __restrict__ W1, const float* __restrict__ W2,
    const float* __restrict__ bias, const float* __restrict__ resid,
    float* __restrict__ C, int N) {
  __shared__ float As[32][68];
  __shared__ float Bs[32][68];

  const int n0 = blockIdx.x * 64;
  const int m0 = blockIdx.y * 64;
  const int tid = threadIdx.x;
  const int tx = tid & 15;   // col group
  const int ty = tid >> 4;   // row group

  const float* Wt;
  int nofs;
  if (MODE == 0) {
    if (n0 < 256) { Wt = W0; nofs = n0; }
    else if (n0 < 512) { Wt = W1; nofs = n0 - 256; }
    else { Wt = W2; nofs = n0 - 512; }
  } else {
    Wt = W0; nofs = n0;
  }

  float acc[4][4] = {};

  for (int kt = 0; kt < 512; kt += 32) {
    // stage A and W tiles: 64 rows x 32 k each, coalesced global reads
#pragma unroll
    for (int i = 0; i < 8; ++i) {
      int idx = tid + i * 256;           // 0..2047
      int kk = idx & 31, r = idx >> 5;
      As[kk][r] = A[(size_t)(m0 + r) * 512 + kt + kk];
      Bs[kk][r] = Wt[(size_t)(nofs + r) * 512 + kt + kk];
    }
    __syncthreads();
#pragma unroll 8
    for (int kk = 0; kk < 32; ++kk) {
      float4 av = *(const float4*)&As[kk][ty * 4];
      float4 bv = *(const float4*)&Bs[kk][tx * 4];
      float aa[4] = {av.x, av.y, av.z, av.w};
      float bb[4] = {bv.x, bv.y, bv.z, bv.w};
#pragma unroll
      for (int i = 0; i < 4; ++i)
#pragma unroll
        for (int j = 0; j < 4; ++j) acc[i][j] += aa[i] * bb[j];
    }
    __syncthreads();
  }

  // epilogue
#pragma unroll
  for (int i = 0; i < 4; ++i) {
    int m = m0 + ty * 4 + i;
    int n = n0 + tx * 4;
    float4 o;
    float vv[4];
#pragma unroll
    for (int j = 0; j < 4; ++j) vv[j] = acc[i][j];
    if (MODE == 1) {
      float4 bv = *(const float4*)&bias[n];
      float4 rv = *(const float4*)&resid[(size_t)m * 512 + n];
      vv[0] += bv.x + rv.x; vv[1] += bv.y + rv.y;
      vv[2] += bv.z + rv.z; vv[3] += bv.w + rv.w;
    } else if (MODE == 2) {
      float4 bv = *(const float4*)&bias[n];
      float4 rv = *(const float4*)&resid[(size_t)m * 512 + n];
      float g0 = vv[0] + bv.x, g1 = vv[1] + bv.y, g2 = vv[2] + bv.z, g3 = vv[3] + bv.w;
      g0 = g0 > 0.f ? g0 : 0.01f * g0;
      g1 = g1 > 0.f ? g1 : 0.01f * g1;
      g2 = g2 > 0.f ? g2 : 0.01f * g2;
      g3 = g3 > 0.f ? g3 : 0.01f * g3;
      vv[0] = rv.x + g0; vv[1] = rv.y + g1; vv[2] = rv.z + g2; vv[3] = rv.w + g3;
    }
    o.x = vv[0]; o.y = vv[1]; o.z = vv[2]; o.w = vv[3];
    *(float4*)&C[(size_t)m * N + n] = o;
  }
}

// ---------------------------------------------------------------------------
// L2-normalize q and k segments in-place. qkv is [8192][1024]:
// cols 0..255 = q (8 heads x 32), 256..511 = k, 512..1023 = v (untouched).
// One thread per 32-element group. 131072 groups.
// ---------------------------------------------------------------------------
__global__ __launch_bounds__(256) void l2norm_qk(float* __restrict__ qkv) {
  int g = blockIdx.x * 256 + threadIdx.x;
  int m = g >> 4, sub = g & 15;
  float* p = qkv + (size_t)m * 1024 + sub * 32;
  float4 v[8];
  float ss = 0.0f;
#pragma unroll
  for (int i = 0; i < 8; ++i) {
    v[i] = ((float4*)p)[i];
    ss += v[i].x * v[i].x + v[i].y * v[i].y + v[i].z * v[i].z + v[i].w * v[i].w;
  }
  float sc = 1.0f / fmaxf(sqrtf(ss), 1e-12f);
#pragma unroll
  for (int i = 0; i < 8; ++i) {
    v[i].x *= sc; v[i].y *= sc; v[i].z *= sc; v[i].w *= sc;
    ((float4*)p)[i] = v[i];
  }
}

// ---------------------------------------------------------------------------
// Causal attention, one block per (s-tile of 64, head, batch).
// Reference softmax: z = exp(score + (exp(-omega*d)-1)); attn = z/(sum z + 1).
// Scores bounded (|cos|<=1, bias in [-0.63,0]) => no max-subtraction needed.
// Stage 1: scores^T tile [t][s] via q@k^T; Stage 2: y += z^T-tile @ v-tile.
// ---------------------------------------------------------------------------
__global__ __launch_bounds__(256) void attn_kernel(
    const float* __restrict__ qkv, const float* __restrict__ dist,
    const float* __restrict__ omega, float* __restrict__ y) {
  __shared__ float qs[32][68];   // [k][s]
  __shared__ float ks[32][68];   // [k][t]
  __shared__ float vs[64][68];   // [t][vd]
  __shared__ float zs[64][68];   // [t][s]
  __shared__ float psum[16][68]; // partial row sums [ty][s]
  __shared__ float zacc[64];     // running denom per s

  const int s0 = blockIdx.x * 64;
  const int h = blockIdx.y;
  const int b = blockIdx.z;
  const int tid = threadIdx.x;
  const int tx = tid & 15, ty = tid >> 4;
  const float om = omega[h];
  const size_t rowbase = (size_t)b * SS;

  // load q tile [32 k][64 s]
#pragma unroll
  for (int i = 0; i < 8; ++i) {
    int idx = tid + i * 256;
    int kk = idx & 31, r = idx >> 5;
    qs[kk][r] = qkv[(rowbase + s0 + r) * 1024 + h * 32 + kk];
  }
  if (tid < 64) zacc[tid] = 0.0f;

  float acc2[4][4] = {};
  const int ntiles = (s0 >> 6) + 1;

  for (int tt = 0; tt < ntiles; ++tt) {
    const int t0 = tt * 64;
    __syncthreads();  // protect zs/vs/ks/psum from previous iteration
    // load k tile [32][64] and v tile [64][64]
#pragma unroll
    for (int i = 0; i < 8; ++i) {
      int idx = tid + i * 256;
      int kk = idx & 31, r = idx >> 5;
      ks[kk][r] = qkv[(rowbase + t0 + r) * 1024 + 256 + h * 32 + kk];
    }
#pragma unroll
    for (int i = 0; i < 16; ++i) {
      int idx = tid + i * 256;
      int vd = idx & 63, r = idx >> 6;
      vs[r][vd] = qkv[(rowbase + t0 + r) * 1024 + 512 + h * 64 + vd];
    }
    __syncthreads();

    // stage 1: scores; thread owns rows t = t0+4ty+i, cols s = s0+4tx+j
    float a1[4][4] = {};
#pragma unroll 8
    for (int kk = 0; kk < 32; ++kk) {
      float4 kv = *(const float4*)&ks[kk][ty * 4];
      float4 qv = *(const float4*)&qs[kk][tx * 4];
      float ka[4] = {kv.x, kv.y, kv.z, kv.w};
      float qa[4] = {qv.x, qv.y, qv.z, qv.w};
#pragma unroll
      for (int i = 0; i < 4; ++i)
#pragma unroll
        for (int j = 0; j < 4; ++j) a1[i][j] += ka[i] * qa[j];
    }
    // mask + distance bias + exp; write zs[t][s], row-sum partials
    float ps[4] = {0.f, 0.f, 0.f, 0.f};
#pragma unroll
    for (int i = 0; i < 4; ++i) {
      int t = t0 + ty * 4 + i;
#pragma unroll
      for (int j = 0; j < 4; ++j) {
        int s = s0 + tx * 4 + j;
        float zv = 0.0f;
        if (t <= s) {
          float d = dist[(rowbase + s) * SS + t];
          float rb = __expf(-om * d) - 1.0f;
          zv = __expf(a1[i][j] + rb);
        }
        zs[ty * 4 + i][tx * 4 + j] = zv;
        ps[j] += zv;
      }
    }
#pragma unroll
    for (int j = 0; j < 4; ++j) psum[ty][tx * 4 + j] = ps[j];
    __syncthreads();

    if (tid < 64) {
      float a = 0.f;
#pragma unroll
      for (int w2 = 0; w2 < 16; ++w2) a += psum[w2][tid];
      zacc[tid] += a;
    }
    // stage 2: y-acc; thread owns rows s = 4ty+i, cols vd = 4tx+j
#pragma unroll 8
    for (int t = 0; t < 64; ++t) {
      float4 zv4 = *(const float4*)&zs[t][ty * 4];
      float4 vv4 = *(const float4*)&vs[t][tx * 4];
      float za[4] = {zv4.x, zv4.y, zv4.z, zv4.w};
      float va[4] = {vv4.x, vv4.y, vv4.z, vv4.w};
#pragma unroll
      for (int i = 0; i < 4; ++i)
#pragma unroll
        for (int j = 0; j < 4; ++j) acc2[i][j] += za[i] * va[j];
    }
  }
  __syncthreads();

  // write y[b,s,h*64+vd] = acc2 / (zacc + 1)
#pragma unroll
  for (int i = 0; i < 4; ++i) {
    int sl = ty * 4 + i;
    float inv = 1.0f / (zacc[sl] + 1.0f);
    float4 o;
    o.x = acc2[i][0] * inv; o.y = acc2[i][1] * inv;
    o.z = acc2[i][2] * inv; o.w = acc2[i][3] * inv;
    *(float4*)&y[(rowbase + s0 + sl) * 512 + h * 64 + tx * 4] = o;
  }
}

// ---------------------------------------------------------------------------
// Row-wise LayerNorm over 512 elems; one block (256 thr) per row; in-place ok.
// ---------------------------------------------------------------------------
__global__ __launch_bounds__(256) void ln_kernel(
    const float* __restrict__ in, const float* __restrict__ w,
    const float* __restrict__ bvec, float* __restrict__ out) {
  __shared__ float sbuf[4];
  const int m = blockIdx.x;
  const int tid = threadIdx.x;
  const float2 v = ((const float2*)(in + (size_t)m * 512))[tid];
  float s = v.x + v.y;
#pragma unroll
  for (int off = 32; off > 0; off >>= 1) s += __shfl_down(s, off, 64);
  const int lane = tid & 63, wid = tid >> 6;
  if (lane == 0) sbuf[wid] = s;
  __syncthreads();
  const float mu = (sbuf[0] + sbuf[1] + sbuf[2] + sbuf[3]) * (1.0f / 512.0f);
  __syncthreads();
  const float dx = v.x - mu, dy = v.y - mu;
  float s2 = dx * dx + dy * dy;
#pragma unroll
  for (int off = 32; off > 0; off >>= 1) s2 += __shfl_down(s2, off, 64);
  if (lane == 0) sbuf[wid] = s2;
  __syncthreads();
  const float var = (sbuf[0] + sbuf[1] + sbuf[2] + sbuf[3]) * (1.0f / 512.0f);
  const float inv = rsqrtf(var + 1e-5f);
  const float2 wv = ((const float2*)w)[tid];
  const float2 bv = ((const float2*)bvec)[tid];
  float2 o;
  o.x = dx * inv * wv.x + bv.x;
  o.y = dy * inv * wv.y + bv.y;
  ((float2*)(out + (size_t)m * 512))[tid] = o;
}

// ---------------------------------------------------------------------------
extern "C" void kernel_launch(void* const* d_in, const int* in_sizes, int n_in,
                              void* d_out, int out_size, void* d_ws, size_t ws_size,
                              hipStream_t stream) {
  const float* x = (const float*)d_in[0];
  // d_in[1] = attn_mask: deterministic causal triu(k=1) -> handled analytically
  const float* dist = (const float*)d_in[2];
  const float* Wq = (const float*)d_in[3];
  const float* Wk = (const float*)d_in[4];
  const float* Wv = (const float*)d_in[5];
  const float* omega = (const float*)d_in[6];
  const float* Wo = (const float*)d_in[7];
  const float* bo = (const float*)d_in[8];
  const float* Wf = (const float*)d_in[9];
  const float* bf_ = (const float*)d_in[10];
  const float* ln1w = (const float*)d_in[11];
  const float* ln1b = (const float*)d_in[12];
  const float* ln2w = (const float*)d_in[13];
  const float* ln2b = (const float*)d_in[14];
  float* out = (float*)d_out;

  float* ws = (float*)d_ws;
  float* qkv = ws;                        // [8192][1024]  32 MB
  float* ybuf = ws + (size_t)8192 * 1024; // [8192][512]   16 MB
  float* t1 = ws;                         // reuse qkv region after attention

  dim3 blk(256);
  // 1. QKV projection -> qkv
  gemm_xwt<0><<<dim3(16, 128), blk, 0, stream>>>(x, Wq, Wk, Wv, nullptr, nullptr,
                                                 qkv, 1024);
  // 2. L2-normalize q,k in-place
  l2norm_qk<<<dim3(512), blk, 0, stream>>>(qkv);
  // 3. causal attention -> ybuf ([b,s,h*64+vd] = concat heads)
  attn_kernel<<<dim3(16, 8, 8), blk, 0, stream>>>(qkv, dist, omega, ybuf);
  // 4. out-proj + bias + residual -> t1 (recycles qkv region)
  gemm_xwt<1><<<dim3(8, 128), blk, 0, stream>>>(ybuf, Wo, nullptr, nullptr, bo, x,
                                                t1, 512);
  // 5. LayerNorm1 in-place (t1 -> z1)
  ln_kernel<<<dim3(8192), blk, 0, stream>>>(t1, ln1w, ln1b, t1);
  // 6. FFN + leaky-relu + residual -> h2 (recycles ybuf)
  gemm_xwt<2><<<dim3(8, 128), blk, 0, stream>>>(t1, Wf, nullptr, nullptr, bf_, t1,
                                                ybuf, 512);
  // 7. LayerNorm2 -> out
  ln_kernel<<<dim3(8192), blk, 0, stream>>>(ybuf, ln2w, ln2b, out);
}

// Round 2
// 602.112 us; speedup vs baseline: 1.1332x; 1.1332x over previous
//
#include <hip/hip_runtime.h>
#include <math.h>

// Problem constants
#define BB 8
#define SS 1024
#define DMM 512
#define HH 8
#define DKK 32
#define DHH 64
// M = BB*SS = 8192

// ---------------------------------------------------------------------------
// Generic tiled GEMM: C[M,N] = A[M,512] @ W[N,512]^T  (+ epilogue per MODE)
// MODE 0: QKV projection, W split across Wq(256)/Wk(256)/Wv(512) regions, N=1024
// MODE 1: C = A@Wo^T + bias + resid               (N=512)
// MODE 2: C = resid + leaky_relu(A@Wf^T + bias)   (N=512)
// Tile 64x64, BK=32, 256 threads, 4x4 per thread.
// ---------------------------------------------------------------------------
template <int MODE>
__global__ __launch_bounds__(256) void gemm_xwt(
    const float* __restrict__ A, const float* __restrict__ W0,
    const float* __restrict__ W1, const float* __restrict__ W2,
    const float* __restrict__ bias, const float* __restrict__ resid,
    float* __restrict__ C, int N) {
  __shared__ float As[32][68];
  __shared__ float Bs[32][68];

  const int n0 = blockIdx.x * 64;
  const int m0 = blockIdx.y * 64;
  const int tid = threadIdx.x;
  const int tx = tid & 15;   // col group
  const int ty = tid >> 4;   // row group

  const float* Wt;
  int nofs;
  if (MODE == 0) {
    if (n0 < 256) { Wt = W0; nofs = n0; }
    else if (n0 < 512) { Wt = W1; nofs = n0 - 256; }
    else { Wt = W2; nofs = n0 - 512; }
  } else {
    Wt = W0; nofs = n0;
  }

  float acc[4][4] = {};

  for (int kt = 0; kt < 512; kt += 32) {
#pragma unroll
    for (int i = 0; i < 8; ++i) {
      int idx = tid + i * 256;           // 0..2047
      int kk = idx & 31, r = idx >> 5;
      As[kk][r] = A[(size_t)(m0 + r) * 512 + kt + kk];
      Bs[kk][r] = Wt[(size_t)(nofs + r) * 512 + kt + kk];
    }
    __syncthreads();
#pragma unroll 8
    for (int kk = 0; kk < 32; ++kk) {
      float4 av = *(const float4*)&As[kk][ty * 4];
      float4 bv = *(const float4*)&Bs[kk][tx * 4];
      float aa[4] = {av.x, av.y, av.z, av.w};
      float bb[4] = {bv.x, bv.y, bv.z, bv.w};
#pragma unroll
      for (int i = 0; i < 4; ++i)
#pragma unroll
        for (int j = 0; j < 4; ++j) acc[i][j] += aa[i] * bb[j];
    }
    __syncthreads();
  }

  // epilogue
#pragma unroll
  for (int i = 0; i < 4; ++i) {
    int m = m0 + ty * 4 + i;
    int n = n0 + tx * 4;
    float4 o;
    float vv[4];
#pragma unroll
    for (int j = 0; j < 4; ++j) vv[j] = acc[i][j];
    if (MODE == 1) {
      float4 bv = *(const float4*)&bias[n];
      float4 rv = *(const float4*)&resid[(size_t)m * 512 + n];
      vv[0] += bv.x + rv.x; vv[1] += bv.y + rv.y;
      vv[2] += bv.z + rv.z; vv[3] += bv.w + rv.w;
    } else if (MODE == 2) {
      float4 bv = *(const float4*)&bias[n];
      float4 rv = *(const float4*)&resid[(size_t)m * 512 + n];
      float g0 = vv[0] + bv.x, g1 = vv[1] + bv.y, g2 = vv[2] + bv.z, g3 = vv[3] + bv.w;
      g0 = g0 > 0.f ? g0 : 0.01f * g0;
      g1 = g1 > 0.f ? g1 : 0.01f * g1;
      g2 = g2 > 0.f ? g2 : 0.01f * g2;
      g3 = g3 > 0.f ? g3 : 0.01f * g3;
      vv[0] = rv.x + g0; vv[1] = rv.y + g1; vv[2] = rv.z + g2; vv[3] = rv.w + g3;
    }
    o.x = vv[0]; o.y = vv[1]; o.z = vv[2]; o.w = vv[3];
    *(float4*)&C[(size_t)m * N + n] = o;
  }
}

// ---------------------------------------------------------------------------
// L2-normalize q and k segments in-place (qkv: [8192][1024], q=0..255 k=256..511)
// ---------------------------------------------------------------------------
__global__ __launch_bounds__(256) void l2norm_qk(float* __restrict__ qkv) {
  int g = blockIdx.x * 256 + threadIdx.x;
  int m = g >> 4, sub = g & 15;
  float* p = qkv + (size_t)m * 1024 + sub * 32;
  float4 v[8];
  float ss = 0.0f;
#pragma unroll
  for (int i = 0; i < 8; ++i) {
    v[i] = ((float4*)p)[i];
    ss += v[i].x * v[i].x + v[i].y * v[i].y + v[i].z * v[i].z + v[i].w * v[i].w;
  }
  float sc = 1.0f / fmaxf(sqrtf(ss), 1e-12f);
#pragma unroll
  for (int i = 0; i < 8; ++i) {
    v[i].x *= sc; v[i].y *= sc; v[i].z *= sc; v[i].w *= sc;
    ((float4*)p)[i] = v[i];
  }
}

// ---------------------------------------------------------------------------
// Causal attention. Changes vs R1:
//  - dist loads are float4 along t (coalesced), prefetched before stage-1 FMAs
//  - denominator accumulated in registers during stage 2 (psum/zacc LDS gone)
//  - LDS 52224 B -> 3 blocks/CU (was 56832 -> 2)
//  - grid (b, s_tile, h) with heavy s-tiles first; b on x for XCD/L2 affinity
// ---------------------------------------------------------------------------
__global__ __launch_bounds__(256) void attn_kernel(
    const float* __restrict__ qkv, const float* __restrict__ dist,
    const float* __restrict__ omega, float* __restrict__ y) {
  __shared__ float qs[32][68];   // [k][s]
  __shared__ float ks[32][68];   // [k][t]
  __shared__ float vs[64][68];   // [t][vd]
  __shared__ float zs[64][68];   // [t][s]

  const int b = blockIdx.x;
  const int s0 = (15 - blockIdx.y) * 64;   // heavy blocks dispatch first
  const int h = blockIdx.z;
  const int tid = threadIdx.x;
  const int tx = tid & 15, ty = tid >> 4;
  const float om = omega[h];
  const size_t rowbase = (size_t)b * SS;

  // load q tile [32 k][64 s]
#pragma unroll
  for (int i = 0; i < 8; ++i) {
    int idx = tid + i * 256;
    int kk = idx & 31, r = idx >> 5;
    qs[kk][r] = qkv[(rowbase + s0 + r) * 1024 + h * 32 + kk];
  }

  float acc2[4][4] = {};
  float zsum[4] = {0.f, 0.f, 0.f, 0.f};
  const int ntiles = (s0 >> 6) + 1;

  for (int tt = 0; tt < ntiles; ++tt) {
    const int t0 = tt * 64;
    __syncthreads();  // prev stage-2 done (zs/vs/ks reusable); qs visible
    // load k tile [32][64] and v tile [64][64]
#pragma unroll
    for (int i = 0; i < 8; ++i) {
      int idx = tid + i * 256;
      int kk = idx & 31, r = idx >> 5;
      ks[kk][r] = qkv[(rowbase + t0 + r) * 1024 + 256 + h * 32 + kk];
    }
#pragma unroll
    for (int i = 0; i < 16; ++i) {
      int idx = tid + i * 256;
      int vd = idx & 63, r = idx >> 6;
      vs[r][vd] = qkv[(rowbase + t0 + r) * 1024 + 512 + h * 64 + vd];
    }
    __syncthreads();

    // prefetch dist: thread needs (s = s0+4tx+j, t = t0+4ty+i); t contiguous
    float4 dv[4];
#pragma unroll
    for (int j = 0; j < 4; ++j) {
      int s = s0 + tx * 4 + j;
      if (t0 + ty * 4 <= s)
        dv[j] = *(const float4*)&dist[(rowbase + s) * SS + t0 + ty * 4];
    }

    // stage 1: scores; thread owns rows t = t0+4ty+i, cols s = s0+4tx+j
    float a1[4][4] = {};
#pragma unroll 8
    for (int kk = 0; kk < 32; ++kk) {
      float4 kv = *(const float4*)&ks[kk][ty * 4];
      float4 qv = *(const float4*)&qs[kk][tx * 4];
      float ka[4] = {kv.x, kv.y, kv.z, kv.w};
      float qa[4] = {qv.x, qv.y, qv.z, qv.w};
#pragma unroll
      for (int i = 0; i < 4; ++i)
#pragma unroll
        for (int j = 0; j < 4; ++j) a1[i][j] += ka[i] * qa[j];
    }
    // mask + distance bias + exp -> zs[t][s]
#pragma unroll
    for (int j = 0; j < 4; ++j) {
      int s = s0 + tx * 4 + j;
      float dvf[4] = {dv[j].x, dv[j].y, dv[j].z, dv[j].w};
#pragma unroll
      for (int i = 0; i < 4; ++i) {
        int t = t0 + ty * 4 + i;
        float zv = 0.0f;
        if (t <= s) zv = __expf(a1[i][j] + __expf(-om * dvf[i]) - 1.0f);
        zs[ty * 4 + i][tx * 4 + j] = zv;
      }
    }
    __syncthreads();

    // stage 2: y-acc + denom; thread owns rows s = 4ty+i, cols vd = 4tx+j
#pragma unroll 8
    for (int t = 0; t < 64; ++t) {
      float4 zv4 = *(const float4*)&zs[t][ty * 4];
      float4 vv4 = *(const float4*)&vs[t][tx * 4];
      float za[4] = {zv4.x, zv4.y, zv4.z, zv4.w};
      float va[4] = {vv4.x, vv4.y, vv4.z, vv4.w};
#pragma unroll
      for (int i = 0; i < 4; ++i) {
        zsum[i] += za[i];
#pragma unroll
        for (int j = 0; j < 4; ++j) acc2[i][j] += za[i] * va[j];
      }
    }
  }

  // write y[b,s,h*64+vd] = acc2 / (zsum + 1)
#pragma unroll
  for (int i = 0; i < 4; ++i) {
    int sl = ty * 4 + i;
    float inv = 1.0f / (zsum[i] + 1.0f);
    float4 o;
    o.x = acc2[i][0] * inv; o.y = acc2[i][1] * inv;
    o.z = acc2[i][2] * inv; o.w = acc2[i][3] * inv;
    *(float4*)&y[(rowbase + s0 + sl) * 512 + h * 64 + tx * 4] = o;
  }
}

// ---------------------------------------------------------------------------
// Row-wise LayerNorm over 512 elems; one block (256 thr) per row; in-place ok.
// ---------------------------------------------------------------------------
__global__ __launch_bounds__(256) void ln_kernel(
    const float* __restrict__ in, const float* __restrict__ w,
    const float* __restrict__ bvec, float* __restrict__ out) {
  __shared__ float sbuf[4];
  const int m = blockIdx.x;
  const int tid = threadIdx.x;
  const float2 v = ((const float2*)(in + (size_t)m * 512))[tid];
  float s = v.x + v.y;
#pragma unroll
  for (int off = 32; off > 0; off >>= 1) s += __shfl_down(s, off, 64);
  const int lane = tid & 63, wid = tid >> 6;
  if (lane == 0) sbuf[wid] = s;
  __syncthreads();
  const float mu = (sbuf[0] + sbuf[1] + sbuf[2] + sbuf[3]) * (1.0f / 512.0f);
  __syncthreads();
  const float dx = v.x - mu, dy = v.y - mu;
  float s2 = dx * dx + dy * dy;
#pragma unroll
  for (int off = 32; off > 0; off >>= 1) s2 += __shfl_down(s2, off, 64);
  if (lane == 0) sbuf[wid] = s2;
  __syncthreads();
  const float var = (sbuf[0] + sbuf[1] + sbuf[2] + sbuf[3]) * (1.0f / 512.0f);
  const float inv = rsqrtf(var + 1e-5f);
  const float2 wv = ((const float2*)w)[tid];
  const float2 bv = ((const float2*)bvec)[tid];
  float2 o;
  o.x = dx * inv * wv.x + bv.x;
  o.y = dy * inv * wv.y + bv.y;
  ((float2*)(out + (size_t)m * 512))[tid] = o;
}

// ---------------------------------------------------------------------------
extern "C" void kernel_launch(void* const* d_in, const int* in_sizes, int n_in,
                              void* d_out, int out_size, void* d_ws, size_t ws_size,
                              hipStream_t stream) {
  const float* x = (const float*)d_in[0];
  // d_in[1] = attn_mask: deterministic causal triu(k=1) -> handled analytically
  const float* dist = (const float*)d_in[2];
  const float* Wq = (const float*)d_in[3];
  const float* Wk = (const float*)d_in[4];
  const float* Wv = (const float*)d_in[5];
  const float* omega = (const float*)d_in[6];
  const float* Wo = (const float*)d_in[7];
  const float* bo = (const float*)d_in[8];
  const float* Wf = (const float*)d_in[9];
  const float* bf_ = (const float*)d_in[10];
  const float* ln1w = (const float*)d_in[11];
  const float* ln1b = (const float*)d_in[12];
  const float* ln2w = (const float*)d_in[13];
  const float* ln2b = (const float*)d_in[14];
  float* out = (float*)d_out;

  float* ws = (float*)d_ws;
  float* qkv = ws;                        // [8192][1024]  32 MB
  float* ybuf = ws + (size_t)8192 * 1024; // [8192][512]   16 MB
  float* t1 = ws;                         // reuse qkv region after attention

  dim3 blk(256);
  // 1. QKV projection -> qkv
  gemm_xwt<0><<<dim3(16, 128), blk, 0, stream>>>(x, Wq, Wk, Wv, nullptr, nullptr,
                                                 qkv, 1024);
  // 2. L2-normalize q,k in-place
  l2norm_qk<<<dim3(512), blk, 0, stream>>>(qkv);
  // 3. causal attention -> ybuf ([b,s,h*64+vd] = concat heads)
  attn_kernel<<<dim3(8, 16, 8), blk, 0, stream>>>(qkv, dist, omega, ybuf);
  // 4. out-proj + bias + residual -> t1 (recycles qkv region)
  gemm_xwt<1><<<dim3(8, 128), blk, 0, stream>>>(ybuf, Wo, nullptr, nullptr, bo, x,
                                                t1, 512);
  // 5. LayerNorm1 in-place (t1 -> z1)
  ln_kernel<<<dim3(8192), blk, 0, stream>>>(t1, ln1w, ln1b, t1);
  // 6. FFN + leaky-relu + residual -> h2 (recycles ybuf)
  gemm_xwt<2><<<dim3(8, 128), blk, 0, stream>>>(t1, Wf, nullptr, nullptr, bf_, t1,
                                                ybuf, 512);
  // 7. LayerNorm2 -> out
  ln_kernel<<<dim3(8192), blk, 0, stream>>>(ybuf, ln2w, ln2b, out);
}

// Round 3
// 417.194 us; speedup vs baseline: 1.6355x; 1.4432x over previous
//
#include <hip/hip_runtime.h>
#include <hip/hip_bf16.h>
#include <math.h>

// Problem constants
#define BB 8
#define SS 1024
#define DMM 512
#define HH 8
#define DKK 32
#define DHH 64
// M = BB*SS = 8192

typedef __bf16 bf16x8 __attribute__((ext_vector_type(8)));
typedef float f32x4 __attribute__((ext_vector_type(4)));

// ---------------------------------------------------------------------------
// bf16-MFMA GEMM: C[M,N] = A[M,512] @ W[N,512]^T (+ epilogue per MODE)
// fp32 inputs converted to bf16 during LDS staging (v_cvt_pk), fp32 accum.
// MODE 0: QKV projection, W regions Wq(256)/Wk(256)/Wv(512), N=1024
// MODE 1: C = A@Wo^T + bias + resid               (N=512)
// MODE 2: C = resid + leaky_relu(A@Wf^T + bias)   (N=512)
// Tile 128x128, BK=32, 256 thr = 4 waves (2x2), each wave 64x64 via 4x4
// mfma_f32_16x16x32_bf16. LDS rows padded to 40 bf16 (80 B): 16B-aligned
// ds_read_b128, 2-way bank aliasing (free).
// ---------------------------------------------------------------------------
template <int MODE>
__global__ __launch_bounds__(256) void gemm_mfma(
    const float* __restrict__ A, const float* __restrict__ W0,
    const float* __restrict__ W1, const float* __restrict__ W2,
    const float* __restrict__ bias, const float* __restrict__ resid,
    float* __restrict__ C, int N) {
  __shared__ __bf16 As[128][40];
  __shared__ __bf16 Bs[128][40];

  const int tid = threadIdx.x;
  const int n0 = blockIdx.x * 128;
  const int m0 = blockIdx.y * 128;

  const float* Wt;
  int nofs;
  if (MODE == 0) {
    if (n0 < 256) { Wt = W0; nofs = n0; }
    else if (n0 < 512) { Wt = W1; nofs = n0 - 256; }
    else { Wt = W2; nofs = n0 - 512; }
  } else {
    Wt = W0; nofs = n0;
  }

  const int lane = tid & 63;
  const int w = tid >> 6;
  const int wm = (w & 1) * 64;   // wave sub-tile origin (rows)
  const int wn = (w >> 1) * 64;  // wave sub-tile origin (cols)
  const int fr = lane & 15;      // fragment row/col index
  const int fk = (lane >> 4) * 8;  // fragment k base

  f32x4 acc[4][4];
#pragma unroll
  for (int mi = 0; mi < 4; ++mi)
#pragma unroll
    for (int ni = 0; ni < 4; ++ni) acc[mi][ni] = (f32x4){0.f, 0.f, 0.f, 0.f};

  for (int kt = 0; kt < 512; kt += 32) {
    __syncthreads();  // previous iteration's LDS reads done
    // stage A,W tiles (128 rows x 32 k fp32 -> bf16). Thread: 4 float4 each.
#pragma unroll
    for (int i = 0; i < 4; ++i) {
      int q = tid + i * 256;          // 0..1023
      int r = q >> 3, k4 = (q & 7) * 4;
      float4 av = *(const float4*)&A[(size_t)(m0 + r) * 512 + kt + k4];
      float4 bv = *(const float4*)&Wt[(size_t)(nofs + r) * 512 + kt + k4];
      union { __hip_bfloat162 h2[2]; uint2 u; } pa, pb;
      pa.h2[0] = __float22bfloat162_rn(make_float2(av.x, av.y));
      pa.h2[1] = __float22bfloat162_rn(make_float2(av.z, av.w));
      pb.h2[0] = __float22bfloat162_rn(make_float2(bv.x, bv.y));
      pb.h2[1] = __float22bfloat162_rn(make_float2(bv.z, bv.w));
      *(uint2*)&As[r][k4] = pa.u;     // ds_write_b64
      *(uint2*)&Bs[r][k4] = pb.u;
    }
    __syncthreads();

    bf16x8 af[4], bf[4];
#pragma unroll
    for (int mi = 0; mi < 4; ++mi)
      af[mi] = *(const bf16x8*)&As[wm + mi * 16 + fr][fk];
#pragma unroll
    for (int ni = 0; ni < 4; ++ni)
      bf[ni] = *(const bf16x8*)&Bs[wn + ni * 16 + fr][fk];
#pragma unroll
    for (int mi = 0; mi < 4; ++mi)
#pragma unroll
      for (int ni = 0; ni < 4; ++ni)
        acc[mi][ni] = __builtin_amdgcn_mfma_f32_16x16x32_bf16(
            af[mi], bf[ni], acc[mi][ni], 0, 0, 0);
  }

  // epilogue: C/D layout col = lane&15, row = (lane>>4)*4 + reg
  const int er = (lane >> 4) * 4;
  const int ec = lane & 15;
#pragma unroll
  for (int mi = 0; mi < 4; ++mi) {
#pragma unroll
    for (int ni = 0; ni < 4; ++ni) {
      const int n = n0 + wn + ni * 16 + ec;
      float bsv = (MODE != 0) ? bias[n] : 0.0f;
#pragma unroll
      for (int r = 0; r < 4; ++r) {
        const int m = m0 + wm + mi * 16 + er + r;
        float v = acc[mi][ni][r];
        if (MODE == 1) {
          v += bsv + resid[(size_t)m * 512 + n];
        } else if (MODE == 2) {
          float g = v + bsv;
          g = g > 0.f ? g : 0.01f * g;
          v = resid[(size_t)m * 512 + n] + g;
        }
        C[(size_t)m * N + n] = v;
      }
    }
  }
}

// ---------------------------------------------------------------------------
// L2-normalize q and k segments in-place (qkv: [8192][1024], q=0..255 k=256..511)
// ---------------------------------------------------------------------------
__global__ __launch_bounds__(256) void l2norm_qk(float* __restrict__ qkv) {
  int g = blockIdx.x * 256 + threadIdx.x;
  int m = g >> 4, sub = g & 15;
  float* p = qkv + (size_t)m * 1024 + sub * 32;
  float4 v[8];
  float ss = 0.0f;
#pragma unroll
  for (int i = 0; i < 8; ++i) {
    v[i] = ((float4*)p)[i];
    ss += v[i].x * v[i].x + v[i].y * v[i].y + v[i].z * v[i].z + v[i].w * v[i].w;
  }
  float sc = 1.0f / fmaxf(sqrtf(ss), 1e-12f);
#pragma unroll
  for (int i = 0; i < 8; ++i) {
    v[i].x *= sc; v[i].y *= sc; v[i].z *= sc; v[i].w *= sc;
    ((float4*)p)[i] = v[i];
  }
}

// ---------------------------------------------------------------------------
// Causal attention (unchanged from R2).
// ---------------------------------------------------------------------------
__global__ __launch_bounds__(256) void attn_kernel(
    const float* __restrict__ qkv, const float* __restrict__ dist,
    const float* __restrict__ omega, float* __restrict__ y) {
  __shared__ float qs[32][68];   // [k][s]
  __shared__ float ks[32][68];   // [k][t]
  __shared__ float vs[64][68];   // [t][vd]
  __shared__ float zs[64][68];   // [t][s]

  const int b = blockIdx.x;
  const int s0 = (15 - blockIdx.y) * 64;   // heavy blocks dispatch first
  const int h = blockIdx.z;
  const int tid = threadIdx.x;
  const int tx = tid & 15, ty = tid >> 4;
  const float om = omega[h];
  const size_t rowbase = (size_t)b * SS;

  // load q tile [32 k][64 s]
#pragma unroll
  for (int i = 0; i < 8; ++i) {
    int idx = tid + i * 256;
    int kk = idx & 31, r = idx >> 5;
    qs[kk][r] = qkv[(rowbase + s0 + r) * 1024 + h * 32 + kk];
  }

  float acc2[4][4] = {};
  float zsum[4] = {0.f, 0.f, 0.f, 0.f};
  const int ntiles = (s0 >> 6) + 1;

  for (int tt = 0; tt < ntiles; ++tt) {
    const int t0 = tt * 64;
    __syncthreads();
#pragma unroll
    for (int i = 0; i < 8; ++i) {
      int idx = tid + i * 256;
      int kk = idx & 31, r = idx >> 5;
      ks[kk][r] = qkv[(rowbase + t0 + r) * 1024 + 256 + h * 32 + kk];
    }
#pragma unroll
    for (int i = 0; i < 16; ++i) {
      int idx = tid + i * 256;
      int vd = idx & 63, r = idx >> 6;
      vs[r][vd] = qkv[(rowbase + t0 + r) * 1024 + 512 + h * 64 + vd];
    }
    __syncthreads();

    // prefetch dist: (s = s0+4tx+j, t = t0+4ty+i); t contiguous
    float4 dv[4];
#pragma unroll
    for (int j = 0; j < 4; ++j) {
      int s = s0 + tx * 4 + j;
      if (t0 + ty * 4 <= s)
        dv[j] = *(const float4*)&dist[(rowbase + s) * SS + t0 + ty * 4];
    }

    // stage 1: scores; thread owns rows t = t0+4ty+i, cols s = s0+4tx+j
    float a1[4][4] = {};
#pragma unroll 8
    for (int kk = 0; kk < 32; ++kk) {
      float4 kv = *(const float4*)&ks[kk][ty * 4];
      float4 qv = *(const float4*)&qs[kk][tx * 4];
      float ka[4] = {kv.x, kv.y, kv.z, kv.w};
      float qa[4] = {qv.x, qv.y, qv.z, qv.w};
#pragma unroll
      for (int i = 0; i < 4; ++i)
#pragma unroll
        for (int j = 0; j < 4; ++j) a1[i][j] += ka[i] * qa[j];
    }
#pragma unroll
    for (int j = 0; j < 4; ++j) {
      int s = s0 + tx * 4 + j;
      float dvf[4] = {dv[j].x, dv[j].y, dv[j].z, dv[j].w};
#pragma unroll
      for (int i = 0; i < 4; ++i) {
        int t = t0 + ty * 4 + i;
        float zv = 0.0f;
        if (t <= s) zv = __expf(a1[i][j] + __expf(-om * dvf[i]) - 1.0f);
        zs[ty * 4 + i][tx * 4 + j] = zv;
      }
    }
    __syncthreads();

    // stage 2: y-acc + denom; thread owns rows s = 4ty+i, cols vd = 4tx+j
#pragma unroll 8
    for (int t = 0; t < 64; ++t) {
      float4 zv4 = *(const float4*)&zs[t][ty * 4];
      float4 vv4 = *(const float4*)&vs[t][tx * 4];
      float za[4] = {zv4.x, zv4.y, zv4.z, zv4.w};
      float va[4] = {vv4.x, vv4.y, vv4.z, vv4.w};
#pragma unroll
      for (int i = 0; i < 4; ++i) {
        zsum[i] += za[i];
#pragma unroll
        for (int j = 0; j < 4; ++j) acc2[i][j] += za[i] * va[j];
      }
    }
  }

  // write y[b,s,h*64+vd] = acc2 / (zsum + 1)
#pragma unroll
  for (int i = 0; i < 4; ++i) {
    int sl = ty * 4 + i;
    float inv = 1.0f / (zsum[i] + 1.0f);
    float4 o;
    o.x = acc2[i][0] * inv; o.y = acc2[i][1] * inv;
    o.z = acc2[i][2] * inv; o.w = acc2[i][3] * inv;
    *(float4*)&y[(rowbase + s0 + sl) * 512 + h * 64 + tx * 4] = o;
  }
}

// ---------------------------------------------------------------------------
// Row-wise LayerNorm over 512 elems; one block (256 thr) per row; in-place ok.
// ---------------------------------------------------------------------------
__global__ __launch_bounds__(256) void ln_kernel(
    const float* __restrict__ in, const float* __restrict__ w,
    const float* __restrict__ bvec, float* __restrict__ out) {
  __shared__ float sbuf[4];
  const int m = blockIdx.x;
  const int tid = threadIdx.x;
  const float2 v = ((const float2*)(in + (size_t)m * 512))[tid];
  float s = v.x + v.y;
#pragma unroll
  for (int off = 32; off > 0; off >>= 1) s += __shfl_down(s, off, 64);
  const int lane = tid & 63, wid = tid >> 6;
  if (lane == 0) sbuf[wid] = s;
  __syncthreads();
  const float mu = (sbuf[0] + sbuf[1] + sbuf[2] + sbuf[3]) * (1.0f / 512.0f);
  __syncthreads();
  const float dx = v.x - mu, dy = v.y - mu;
  float s2 = dx * dx + dy * dy;
#pragma unroll
  for (int off = 32; off > 0; off >>= 1) s2 += __shfl_down(s2, off, 64);
  if (lane == 0) sbuf[wid] = s2;
  __syncthreads();
  const float var = (sbuf[0] + sbuf[1] + sbuf[2] + sbuf[3]) * (1.0f / 512.0f);
  const float inv = rsqrtf(var + 1e-5f);
  const float2 wv = ((const float2*)w)[tid];
  const float2 bv = ((const float2*)bvec)[tid];
  float2 o;
  o.x = dx * inv * wv.x + bv.x;
  o.y = dy * inv * wv.y + bv.y;
  ((float2*)(out + (size_t)m * 512))[tid] = o;
}

// ---------------------------------------------------------------------------
extern "C" void kernel_launch(void* const* d_in, const int* in_sizes, int n_in,
                              void* d_out, int out_size, void* d_ws, size_t ws_size,
                              hipStream_t stream) {
  const float* x = (const float*)d_in[0];
  // d_in[1] = attn_mask: deterministic causal triu(k=1) -> handled analytically
  const float* dist = (const float*)d_in[2];
  const float* Wq = (const float*)d_in[3];
  const float* Wk = (const float*)d_in[4];
  const float* Wv = (const float*)d_in[5];
  const float* omega = (const float*)d_in[6];
  const float* Wo = (const float*)d_in[7];
  const float* bo = (const float*)d_in[8];
  const float* Wf = (const float*)d_in[9];
  const float* bf_ = (const float*)d_in[10];
  const float* ln1w = (const float*)d_in[11];
  const float* ln1b = (const float*)d_in[12];
  const float* ln2w = (const float*)d_in[13];
  const float* ln2b = (const float*)d_in[14];
  float* out = (float*)d_out;

  float* ws = (float*)d_ws;
  float* qkv = ws;                        // [8192][1024]  32 MB
  float* ybuf = ws + (size_t)8192 * 1024; // [8192][512]   16 MB
  float* t1 = ws;                         // reuse qkv region after attention

  dim3 blk(256);
  // 1. QKV projection -> qkv (bf16 MFMA)
  gemm_mfma<0><<<dim3(8, 64), blk, 0, stream>>>(x, Wq, Wk, Wv, nullptr, nullptr,
                                                qkv, 1024);
  // 2. L2-normalize q,k in-place
  l2norm_qk<<<dim3(512), blk, 0, stream>>>(qkv);
  // 3. causal attention -> ybuf ([b,s,h*64+vd] = concat heads)
  attn_kernel<<<dim3(8, 16, 8), blk, 0, stream>>>(qkv, dist, omega, ybuf);
  // 4. out-proj + bias + residual -> t1 (recycles qkv region)
  gemm_mfma<1><<<dim3(4, 64), blk, 0, stream>>>(ybuf, Wo, nullptr, nullptr, bo, x,
                                                t1, 512);
  // 5. LayerNorm1 in-place (t1 -> z1)
  ln_kernel<<<dim3(8192), blk, 0, stream>>>(t1, ln1w, ln1b, t1);
  // 6. FFN + leaky-relu + residual -> h2 (recycles ybuf)
  gemm_mfma<2><<<dim3(4, 64), blk, 0, stream>>>(t1, Wf, nullptr, nullptr, bf_, t1,
                                                ybuf, 512);
  // 7. LayerNorm2 -> out
  ln_kernel<<<dim3(8192), blk, 0, stream>>>(ybuf, ln2w, ln2b, out);
}

// Round 4
// 278.515 us; speedup vs baseline: 2.4498x; 1.4979x over previous
//
#include <hip/hip_runtime.h>
#include <hip/hip_bf16.h>
#include <math.h>

// Problem constants
#define BB 8
#define SS 1024
#define DMM 512
#define HH 8
#define DKK 32
#define DHH 64
// M = BB*SS = 8192

typedef __bf16 bf16x8 __attribute__((ext_vector_type(8)));
typedef float f32x4 __attribute__((ext_vector_type(4)));

// ---------------------------------------------------------------------------
// bf16-MFMA GEMM: C[M,N] = A[M,512] @ W[N,512]^T (+ epilogue per MODE)
// (unchanged from R3 — validated)
// ---------------------------------------------------------------------------
template <int MODE>
__global__ __launch_bounds__(256) void gemm_mfma(
    const float* __restrict__ A, const float* __restrict__ W0,
    const float* __restrict__ W1, const float* __restrict__ W2,
    const float* __restrict__ bias, const float* __restrict__ resid,
    float* __restrict__ C, int N) {
  __shared__ __bf16 As[128][40];
  __shared__ __bf16 Bs[128][40];

  const int tid = threadIdx.x;
  const int n0 = blockIdx.x * 128;
  const int m0 = blockIdx.y * 128;

  const float* Wt;
  int nofs;
  if (MODE == 0) {
    if (n0 < 256) { Wt = W0; nofs = n0; }
    else if (n0 < 512) { Wt = W1; nofs = n0 - 256; }
    else { Wt = W2; nofs = n0 - 512; }
  } else {
    Wt = W0; nofs = n0;
  }

  const int lane = tid & 63;
  const int w = tid >> 6;
  const int wm = (w & 1) * 64;
  const int wn = (w >> 1) * 64;
  const int fr = lane & 15;
  const int fk = (lane >> 4) * 8;

  f32x4 acc[4][4];
#pragma unroll
  for (int mi = 0; mi < 4; ++mi)
#pragma unroll
    for (int ni = 0; ni < 4; ++ni) acc[mi][ni] = (f32x4){0.f, 0.f, 0.f, 0.f};

  for (int kt = 0; kt < 512; kt += 32) {
    __syncthreads();
#pragma unroll
    for (int i = 0; i < 4; ++i) {
      int q = tid + i * 256;
      int r = q >> 3, k4 = (q & 7) * 4;
      float4 av = *(const float4*)&A[(size_t)(m0 + r) * 512 + kt + k4];
      float4 bv = *(const float4*)&Wt[(size_t)(nofs + r) * 512 + kt + k4];
      union { __hip_bfloat162 h2[2]; uint2 u; } pa, pb;
      pa.h2[0] = __float22bfloat162_rn(make_float2(av.x, av.y));
      pa.h2[1] = __float22bfloat162_rn(make_float2(av.z, av.w));
      pb.h2[0] = __float22bfloat162_rn(make_float2(bv.x, bv.y));
      pb.h2[1] = __float22bfloat162_rn(make_float2(bv.z, bv.w));
      *(uint2*)&As[r][k4] = pa.u;
      *(uint2*)&Bs[r][k4] = pb.u;
    }
    __syncthreads();

    bf16x8 af[4], bf[4];
#pragma unroll
    for (int mi = 0; mi < 4; ++mi)
      af[mi] = *(const bf16x8*)&As[wm + mi * 16 + fr][fk];
#pragma unroll
    for (int ni = 0; ni < 4; ++ni)
      bf[ni] = *(const bf16x8*)&Bs[wn + ni * 16 + fr][fk];
#pragma unroll
    for (int mi = 0; mi < 4; ++mi)
#pragma unroll
      for (int ni = 0; ni < 4; ++ni)
        acc[mi][ni] = __builtin_amdgcn_mfma_f32_16x16x32_bf16(
            af[mi], bf[ni], acc[mi][ni], 0, 0, 0);
  }

  const int er = (lane >> 4) * 4;
  const int ec = lane & 15;
#pragma unroll
  for (int mi = 0; mi < 4; ++mi) {
#pragma unroll
    for (int ni = 0; ni < 4; ++ni) {
      const int n = n0 + wn + ni * 16 + ec;
      float bsv = (MODE != 0) ? bias[n] : 0.0f;
#pragma unroll
      for (int r = 0; r < 4; ++r) {
        const int m = m0 + wm + mi * 16 + er + r;
        float v = acc[mi][ni][r];
        if (MODE == 1) {
          v += bsv + resid[(size_t)m * 512 + n];
        } else if (MODE == 2) {
          float g = v + bsv;
          g = g > 0.f ? g : 0.01f * g;
          v = resid[(size_t)m * 512 + n] + g;
        }
        C[(size_t)m * N + n] = v;
      }
    }
  }
}

// ---------------------------------------------------------------------------
// Prep: l2norm q,k -> bf16 planes Qg/Kg[bh][1024 s][32 k]; V -> transposed
// bf16 Vt[bh][64 vd][1024 t]. Grid (64 bh, 8 s-chunks of 128), 256 thr.
// ---------------------------------------------------------------------------
__global__ __launch_bounds__(256) void prep_qkv(
    const float* __restrict__ qkv, __bf16* __restrict__ Qg,
    __bf16* __restrict__ Kg, __bf16* __restrict__ Vt) {
  __shared__ __bf16 vt[64][136];  // [vd][128 t + pad]; 272 B pitch (16B mult)
  const int bh = blockIdx.x;
  const int b = bh >> 3, h = bh & 7;
  const int sb = blockIdx.y * 128;
  const int tid = threadIdx.x;

  // --- q,k l2norm + bf16: 2 threads per row ---
  {
    const int row = tid >> 1, half = tid & 1;
    const size_t rb = ((size_t)b * 1024 + sb + row) * 1024;
    // q
    {
      const float* p = qkv + rb + h * 32 + half * 16;
      float4 a[4];
      float ss = 0.f;
#pragma unroll
      for (int i = 0; i < 4; ++i) {
        a[i] = ((const float4*)p)[i];
        ss += a[i].x * a[i].x + a[i].y * a[i].y + a[i].z * a[i].z + a[i].w * a[i].w;
      }
      ss += __shfl_xor(ss, 1, 64);
      float sc = 1.0f / fmaxf(sqrtf(ss), 1e-12f);
      union { __hip_bfloat162 h2[4]; uint4 u; } pk[2];
#pragma unroll
      for (int i = 0; i < 2; ++i) {
        pk[i].h2[0] = __float22bfloat162_rn(make_float2(a[2*i].x * sc, a[2*i].y * sc));
        pk[i].h2[1] = __float22bfloat162_rn(make_float2(a[2*i].z * sc, a[2*i].w * sc));
        pk[i].h2[2] = __float22bfloat162_rn(make_float2(a[2*i+1].x * sc, a[2*i+1].y * sc));
        pk[i].h2[3] = __float22bfloat162_rn(make_float2(a[2*i+1].z * sc, a[2*i+1].w * sc));
      }
      uint4* o = (uint4*)(Qg + ((size_t)bh * 1024 + sb + row) * 32 + half * 16);
      o[0] = pk[0].u; o[1] = pk[1].u;
    }
    // k
    {
      const float* p = qkv + rb + 256 + h * 32 + half * 16;
      float4 a[4];
      float ss = 0.f;
#pragma unroll
      for (int i = 0; i < 4; ++i) {
        a[i] = ((const float4*)p)[i];
        ss += a[i].x * a[i].x + a[i].y * a[i].y + a[i].z * a[i].z + a[i].w * a[i].w;
      }
      ss += __shfl_xor(ss, 1, 64);
      float sc = 1.0f / fmaxf(sqrtf(ss), 1e-12f);
      union { __hip_bfloat162 h2[4]; uint4 u; } pk[2];
#pragma unroll
      for (int i = 0; i < 2; ++i) {
        pk[i].h2[0] = __float22bfloat162_rn(make_float2(a[2*i].x * sc, a[2*i].y * sc));
        pk[i].h2[1] = __float22bfloat162_rn(make_float2(a[2*i].z * sc, a[2*i].w * sc));
        pk[i].h2[2] = __float22bfloat162_rn(make_float2(a[2*i+1].x * sc, a[2*i+1].y * sc));
        pk[i].h2[3] = __float22bfloat162_rn(make_float2(a[2*i+1].z * sc, a[2*i+1].w * sc));
      }
      uint4* o = (uint4*)(Kg + ((size_t)bh * 1024 + sb + row) * 32 + half * 16);
      o[0] = pk[0].u; o[1] = pk[1].u;
    }
  }

  // --- v transpose: read [t][vd] coalesced, LDS-scatter, write [vd][t] ---
#pragma unroll
  for (int i = 0; i < 8; ++i) {
    int idx = tid + i * 256;            // 0..2047
    int t = idx >> 4, vd4 = (idx & 15) * 4;
    float4 v = *(const float4*)&qkv[((size_t)b * 1024 + sb + t) * 1024 + 512 + h * 64 + vd4];
    vt[vd4 + 0][t] = (__bf16)v.x;
    vt[vd4 + 1][t] = (__bf16)v.y;
    vt[vd4 + 2][t] = (__bf16)v.z;
    vt[vd4 + 3][t] = (__bf16)v.w;
  }
  __syncthreads();
  {
    const int vd = tid >> 2, tseg = (tid & 3) * 32;
    uint4* o = (uint4*)(Vt + (size_t)bh * 65536 + (size_t)vd * 1024 + sb + tseg);
#pragma unroll
    for (int j = 0; j < 4; ++j)
      o[j] = *(const uint4*)&vt[vd][tseg + j * 8];
  }
}

// ---------------------------------------------------------------------------
// MFMA causal attention. Block = (b, 64-row s-tile, h), 256 thr = 4 waves.
// Stage 1: S^T tile via A=K(m=t), B=Q(n=s): lane z regs = 4 consecutive t for
//   one s -> b64 write into zs[s][t] (bf16). exp/bias in fp32; zsum per lane.
// Stage 2: Y[s][vd] via A=zs(m=s,k=t), B=Vs(n=vd,k=t), K=64 = 2 MFMA steps.
// Q/K LDS: [row][32k] with 16B-chunk XOR swizzle; Vs: [vd][64t] chunk-swizzled.
// ---------------------------------------------------------------------------
__global__ __launch_bounds__(256) void attn_mfma(
    const __bf16* __restrict__ Qg, const __bf16* __restrict__ Kg,
    const __bf16* __restrict__ Vt, const float* __restrict__ dist,
    const float* __restrict__ omega, float* __restrict__ y) {
  __shared__ __bf16 Qs[64 * 32];
  __shared__ __bf16 Ks[64 * 32];
  __shared__ __bf16 Vs[64 * 64];
  __shared__ __bf16 zs[64][72];

  const int b = blockIdx.x;
  const int s0 = (15 - blockIdx.y) * 64;   // heavy tiles dispatch first
  const int h = blockIdx.z;
  const int bh = b * 8 + h;
  const int tid = threadIdx.x;
  const int lane = tid & 63;
  const int w = tid >> 6;
  const int quad = lane >> 4;
  const int m = lane & 15;
  const float om = omega[h];
  const size_t rowbase = (size_t)b * SS;

  // stage Q tile (64 x 32 bf16), chunk-swizzled
  {
    int row = tid >> 2, p = tid & 3;
    uint4 v = *(const uint4*)(Qg + ((size_t)bh * 1024 + s0 + row) * 32 + p * 8);
    *(uint4*)&Qs[row * 32 + ((p ^ ((row >> 1) & 3)) * 8)] = v;
  }

  const int kswz = (quad ^ ((m >> 1) & 3)) * 8;  // Q/K frag chunk offset
  const int sl = 16 * w + m;                     // this lane's s (stage 1 & 2)

  f32x4 acc[4];
#pragma unroll
  for (int ni = 0; ni < 4; ++ni) acc[ni] = (f32x4){0.f, 0.f, 0.f, 0.f};
  float zsum = 0.0f;
  const int ntiles = (s0 >> 6) + 1;

  for (int tt = 0; tt < ntiles; ++tt) {
    const int t0 = tt * 64;
    __syncthreads();  // prior stage-1/2 LDS reads complete
    // stage K tile
    {
      int row = tid >> 2, p = tid & 3;
      uint4 v = *(const uint4*)(Kg + ((size_t)bh * 1024 + t0 + row) * 32 + p * 8);
      *(uint4*)&Ks[row * 32 + ((p ^ ((row >> 1) & 3)) * 8)] = v;
    }
    // stage V^T tile (64 vd x 64 t), chunk-swizzled
#pragma unroll
    for (int i = 0; i < 2; ++i) {
      int idx = tid + i * 256;
      int vd = idx >> 3, p = idx & 7;
      uint4 v = *(const uint4*)(Vt + (size_t)bh * 65536 + (size_t)vd * 1024 + t0 + p * 8);
      *(uint4*)&Vs[vd * 64 + ((p ^ (vd & 7)) * 8)] = v;
    }
    // prefetch dist: s = s0+sl fixed, t = t0+16mi+quad*4 .. +3 (float4)
    float4 dv[4];
#pragma unroll
    for (int mi = 0; mi < 4; ++mi)
      dv[mi] = *(const float4*)&dist[(rowbase + s0 + sl) * SS + t0 + 16 * mi + quad * 4];
    __syncthreads();  // staging visible

    // stage 1: A = K rows (t), B = Q row (s)
    const bf16x8 bq = *(const bf16x8*)&Qs[sl * 32 + kswz];
    f32x4 sc4[4];
#pragma unroll
    for (int mi = 0; mi < 4; ++mi) {
      const bf16x8 ak = *(const bf16x8*)&Ks[(16 * mi + m) * 32 + kswz];
      sc4[mi] = __builtin_amdgcn_mfma_f32_16x16x32_bf16(
          ak, bq, (f32x4){0.f, 0.f, 0.f, 0.f}, 0, 0, 0);
    }
    // bias + exp; pack 4 consecutive t as b64 into zs[s][t]
    const bool diag = (tt == ntiles - 1);
#pragma unroll
    for (int mi = 0; mi < 4; ++mi) {
      float zr[4];
#pragma unroll
      for (int r = 0; r < 4; ++r) {
        float d = (&dv[mi].x)[r];
        float zv = __expf(sc4[mi][r] + __expf(-om * d) - 1.0f);
        if (diag && (16 * mi + quad * 4 + r) > sl) zv = 0.0f;
        zr[r] = zv;
        zsum += zv;
      }
      union { __hip_bfloat162 h2[2]; uint2 u; } pz;
      pz.h2[0] = __float22bfloat162_rn(make_float2(zr[0], zr[1]));
      pz.h2[1] = __float22bfloat162_rn(make_float2(zr[2], zr[3]));
      *(uint2*)&zs[sl][16 * mi + quad * 4] = pz.u;
    }
    __syncthreads();  // zs visible

    // stage 2: A = zs (m=s, k=t), B = Vs (n=vd, k=t)
    const bf16x8 za0 = *(const bf16x8*)&zs[sl][quad * 8];
    const bf16x8 za1 = *(const bf16x8*)&zs[sl][quad * 8 + 32];
#pragma unroll
    for (int ni = 0; ni < 4; ++ni) {
      const bf16x8 vb0 = *(const bf16x8*)&Vs[(16 * ni + m) * 64 + ((quad ^ (m & 7)) * 8)];
      const bf16x8 vb1 = *(const bf16x8*)&Vs[(16 * ni + m) * 64 + (((quad + 4) ^ (m & 7)) * 8)];
      acc[ni] = __builtin_amdgcn_mfma_f32_16x16x32_bf16(za0, vb0, acc[ni], 0, 0, 0);
      acc[ni] = __builtin_amdgcn_mfma_f32_16x16x32_bf16(za1, vb1, acc[ni], 0, 0, 0);
    }
  }

  // full denominator for this lane's s: sum quads (t-partition)
  zsum += __shfl_xor(zsum, 16, 64);
  zsum += __shfl_xor(zsum, 32, 64);

  // epilogue: lane's C/D rows are s = 16w + quad*4 + r; fetch denom via shfl
#pragma unroll
  for (int r = 0; r < 4; ++r) {
    float dn = __shfl(zsum, quad * 4 + r, 64);
    float inv = 1.0f / (dn + 1.0f);
    float* yp = &y[(rowbase + s0 + 16 * w + quad * 4 + r) * 512 + h * 64 + m];
#pragma unroll
    for (int ni = 0; ni < 4; ++ni)
      yp[16 * ni] = acc[ni][r] * inv;
  }
}

// ---------------------------------------------------------------------------
// Row-wise LayerNorm over 512 elems; one block (256 thr) per row; in-place ok.
// ---------------------------------------------------------------------------
__global__ __launch_bounds__(256) void ln_kernel(
    const float* __restrict__ in, const float* __restrict__ w,
    const float* __restrict__ bvec, float* __restrict__ out) {
  __shared__ float sbuf[4];
  const int m = blockIdx.x;
  const int tid = threadIdx.x;
  const float2 v = ((const float2*)(in + (size_t)m * 512))[tid];
  float s = v.x + v.y;
#pragma unroll
  for (int off = 32; off > 0; off >>= 1) s += __shfl_down(s, off, 64);
  const int lane = tid & 63, wid = tid >> 6;
  if (lane == 0) sbuf[wid] = s;
  __syncthreads();
  const float mu = (sbuf[0] + sbuf[1] + sbuf[2] + sbuf[3]) * (1.0f / 512.0f);
  __syncthreads();
  const float dx = v.x - mu, dy = v.y - mu;
  float s2 = dx * dx + dy * dy;
#pragma unroll
  for (int off = 32; off > 0; off >>= 1) s2 += __shfl_down(s2, off, 64);
  if (lane == 0) sbuf[wid] = s2;
  __syncthreads();
  const float var = (sbuf[0] + sbuf[1] + sbuf[2] + sbuf[3]) * (1.0f / 512.0f);
  const float inv = rsqrtf(var + 1e-5f);
  const float2 wv = ((const float2*)w)[tid];
  const float2 bv = ((const float2*)bvec)[tid];
  float2 o;
  o.x = dx * inv * wv.x + bv.x;
  o.y = dy * inv * wv.y + bv.y;
  ((float2*)(out + (size_t)m * 512))[tid] = o;
}

// ---------------------------------------------------------------------------
extern "C" void kernel_launch(void* const* d_in, const int* in_sizes, int n_in,
                              void* d_out, int out_size, void* d_ws, size_t ws_size,
                              hipStream_t stream) {
  const float* x = (const float*)d_in[0];
  // d_in[1] = attn_mask: deterministic causal triu(k=1) -> handled analytically
  const float* dist = (const float*)d_in[2];
  const float* Wq = (const float*)d_in[3];
  const float* Wk = (const float*)d_in[4];
  const float* Wv = (const float*)d_in[5];
  const float* omega = (const float*)d_in[6];
  const float* Wo = (const float*)d_in[7];
  const float* bo = (const float*)d_in[8];
  const float* Wf = (const float*)d_in[9];
  const float* bf_ = (const float*)d_in[10];
  const float* ln1w = (const float*)d_in[11];
  const float* ln1b = (const float*)d_in[12];
  const float* ln2w = (const float*)d_in[13];
  const float* ln2b = (const float*)d_in[14];
  float* out = (float*)d_out;

  // Workspace map (48 MB):
  //  [0,32MB):  qkv fp32 [8192][1024]   (after attn: y [0,16MB), t1 [16,32MB))
  //  [32,48MB): Qg 4MB | Kg 4MB | Vt 8MB bf16   (after attn: h2 fp32 16MB)
  float* ws = (float*)d_ws;
  float* qkv = ws;
  float* ybuf = ws;                                  // 16 MB, overwrites q/k rows
  float* t1 = ws + (size_t)4 * 1024 * 1024;          // 16 MB
  __bf16* Qg = (__bf16*)(ws + (size_t)8 * 1024 * 1024);
  __bf16* Kg = Qg + (size_t)2 * 1024 * 1024;
  __bf16* Vt = Kg + (size_t)2 * 1024 * 1024;
  float* h2 = ws + (size_t)8 * 1024 * 1024;          // reuses Qg/Kg/Vt region

  dim3 blk(256);
  // 1. QKV projection -> qkv (bf16 MFMA)
  gemm_mfma<0><<<dim3(8, 64), blk, 0, stream>>>(x, Wq, Wk, Wv, nullptr, nullptr,
                                                qkv, 1024);
  // 2. prep: l2norm q,k -> Qg/Kg bf16; V -> Vt (bf16, transposed)
  prep_qkv<<<dim3(64, 8), blk, 0, stream>>>(qkv, Qg, Kg, Vt);
  // 3. MFMA causal attention -> ybuf ([b,s,h*64+vd])
  attn_mfma<<<dim3(8, 16, 8), blk, 0, stream>>>(Qg, Kg, Vt, dist, omega, ybuf);
  // 4. out-proj + bias + residual -> t1
  gemm_mfma<1><<<dim3(4, 64), blk, 0, stream>>>(ybuf, Wo, nullptr, nullptr, bo, x,
                                                t1, 512);
  // 5. LayerNorm1 in-place
  ln_kernel<<<dim3(8192), blk, 0, stream>>>(t1, ln1w, ln1b, t1);
  // 6. FFN + leaky-relu + residual -> h2
  gemm_mfma<2><<<dim3(4, 64), blk, 0, stream>>>(t1, Wf, nullptr, nullptr, bf_, t1,
                                                h2, 512);
  // 7. LayerNorm2 -> out
  ln_kernel<<<dim3(8192), blk, 0, stream>>>(h2, ln2w, ln2b, out);
}

// Round 5
// 263.722 us; speedup vs baseline: 2.5872x; 1.0561x over previous
//
#include <hip/hip_runtime.h>
#include <hip/hip_bf16.h>
#include <math.h>
#include <stdint.h>

// Problem constants
#define BB 8
#define SS 1024
#define DMM 512
#define HH 8
#define DKK 32
#define DHH 64
// M = BB*SS = 8192

typedef __bf16 bf16x8 __attribute__((ext_vector_type(8)));
typedef float f32x4 __attribute__((ext_vector_type(4)));

// async 16B global->LDS (gfx950). LDS dest = wave-uniform base + lane*16.
__device__ __forceinline__ void gll16(const void* g, void* l) {
  __builtin_amdgcn_global_load_lds(
      (const __attribute__((address_space(1))) void*)(uintptr_t)g,
      (__attribute__((address_space(3))) void*)(uint32_t)(uintptr_t)l,
      16, 0, 0);
}

// ---------------------------------------------------------------------------
// fp32 -> bf16 converters (vectorized, 8 elems/thread)
// ---------------------------------------------------------------------------
__device__ __forceinline__ uint4 pack8(const float4 a, const float4 b) {
  union { __hip_bfloat162 h2[4]; uint4 u; } p;
  p.h2[0] = __float22bfloat162_rn(make_float2(a.x, a.y));
  p.h2[1] = __float22bfloat162_rn(make_float2(a.z, a.w));
  p.h2[2] = __float22bfloat162_rn(make_float2(b.x, b.y));
  p.h2[3] = __float22bfloat162_rn(make_float2(b.z, b.w));
  return p.u;
}

__global__ __launch_bounds__(256) void cvt_f32_bf16(
    const float* __restrict__ s, __bf16* __restrict__ d) {
  size_t i = ((size_t)blockIdx.x * 256 + threadIdx.x) * 8;
  float4 a = *(const float4*)&s[i];
  float4 b = *(const float4*)&s[i + 4];
  *(uint4*)&d[i] = pack8(a, b);
}

// Wcat rows: [0,256)=Wq, [256,512)=Wk, [512,1024)=Wv (all [.][512] flat)
__global__ __launch_bounds__(256) void cvt_wqkv(
    const float* __restrict__ Wq, const float* __restrict__ Wk,
    const float* __restrict__ Wv, __bf16* __restrict__ d) {
  size_t i = ((size_t)blockIdx.x * 256 + threadIdx.x) * 8;
  const float* s;
  size_t off;
  if (i < 131072) { s = Wq; off = i; }
  else if (i < 262144) { s = Wk; off = i - 131072; }
  else { s = Wv; off = i - 262144; }
  float4 a = *(const float4*)&s[off];
  float4 b = *(const float4*)&s[off + 4];
  *(uint4*)&d[i] = pack8(a, b);
}

__global__ __launch_bounds__(256) void cvt_wof(
    const float* __restrict__ Wo, const float* __restrict__ Wf,
    __bf16* __restrict__ dWo, __bf16* __restrict__ dWf) {
  size_t i = ((size_t)blockIdx.x * 256 + threadIdx.x) * 8;
  const float* s;
  __bf16* d;
  size_t off;
  if (i < 262144) { s = Wo; d = dWo; off = i; }
  else { s = Wf; d = dWf; off = i - 262144; }
  float4 a = *(const float4*)&s[off];
  float4 b = *(const float4*)&s[off + 4];
  *(uint4*)&d[off] = pack8(a, b);
}

// ---------------------------------------------------------------------------
// bf16-input MFMA GEMM (m97 structure): C[M,N] = A[M,512] @ W[N,512]^T
// MODE 0: plain store. MODE 1: +bias+resid. MODE 2: resid+leaky(v+bias).
// 128x128 tile, BK=32, 4 waves (2x2), 4x4 frags of 16x16x32.
// Staging via global_load_lds width 16 (async, no VGPR round-trip).
// LDS dest is linear (HW constraint) -> XOR swizzle applied to the GLOBAL
// source chunk: csrc=(lane&3)^((lane>>3)&3); frag read chunk=quad^((fr>>1)&3).
// Net bank aliasing on ds_read_b128: exactly 2-way (free, m136).
// ---------------------------------------------------------------------------
template <int MODE>
__global__ __launch_bounds__(256) void gemm_bf16(
    const __bf16* __restrict__ A, const __bf16* __restrict__ W,
    const float* __restrict__ bias, const float* __restrict__ resid,
    float* __restrict__ C, int N) {
  __shared__ __bf16 As[128 * 32];
  __shared__ __bf16 Bs[128 * 32];
  const int tid = threadIdx.x;
  const int n0 = blockIdx.x * 128;
  const int m0 = blockIdx.y * 128;
  const int lane = tid & 63;
  const int w = tid >> 6;
  const int wm = (w & 1) * 64, wn = (w >> 1) * 64;
  const int fr = lane & 15, quad = lane >> 4;

  const int srow = lane >> 2;                      // row within 16-row segment
  const int schunk = (lane & 3) ^ ((lane >> 3) & 3);  // swizzled global chunk

  f32x4 acc[4][4];
#pragma unroll
  for (int mi = 0; mi < 4; ++mi)
#pragma unroll
    for (int ni = 0; ni < 4; ++ni) acc[mi][ni] = (f32x4){0.f, 0.f, 0.f, 0.f};

  for (int kt = 0; kt < 512; kt += 32) {
    __syncthreads();  // prior iter's ds_reads done before LDS overwrite
#pragma unroll
    for (int j = 0; j < 2; ++j) {
      const int seg = w * 2 + j;
      const int row = seg * 16 + srow;
      gll16(&A[(size_t)(m0 + row) * 512 + kt + schunk * 8], &As[seg * 512]);
      gll16(&W[(size_t)(n0 + row) * 512 + kt + schunk * 8], &Bs[seg * 512]);
    }
    __syncthreads();  // vmcnt(0): staged data visible

    bf16x8 af[4], bf[4];
    const int rsw = (quad ^ ((fr >> 1) & 3)) * 8;
#pragma unroll
    for (int mi = 0; mi < 4; ++mi)
      af[mi] = *(const bf16x8*)&As[(wm + mi * 16 + fr) * 32 + rsw];
#pragma unroll
    for (int ni = 0; ni < 4; ++ni)
      bf[ni] = *(const bf16x8*)&Bs[(wn + ni * 16 + fr) * 32 + rsw];
#pragma unroll
    for (int mi = 0; mi < 4; ++mi)
#pragma unroll
      for (int ni = 0; ni < 4; ++ni)
        acc[mi][ni] = __builtin_amdgcn_mfma_f32_16x16x32_bf16(
            af[mi], bf[ni], acc[mi][ni], 0, 0, 0);
  }

  // epilogue: C/D layout col = lane&15, row = (lane>>4)*4 + reg
  const int er = (lane >> 4) * 4;
  const int ec = lane & 15;
#pragma unroll
  for (int mi = 0; mi < 4; ++mi) {
#pragma unroll
    for (int ni = 0; ni < 4; ++ni) {
      const int n = n0 + wn + ni * 16 + ec;
      float bsv = (MODE != 0) ? bias[n] : 0.0f;
#pragma unroll
      for (int r = 0; r < 4; ++r) {
        const int m = m0 + wm + mi * 16 + er + r;
        float v = acc[mi][ni][r];
        if (MODE == 1) {
          v += bsv + resid[(size_t)m * 512 + n];
        } else if (MODE == 2) {
          float g = v + bsv;
          g = g > 0.f ? g : 0.01f * g;
          v = resid[(size_t)m * 512 + n] + g;
        }
        C[(size_t)m * N + n] = v;
      }
    }
  }
}

// ---------------------------------------------------------------------------
// Prep: l2norm q,k -> bf16 planes Qg/Kg[bh][1024 s][32 k]; V -> transposed
// bf16 Vt[bh][64 vd][1024 t]. Grid (64 bh, 8 s-chunks of 128), 256 thr.
// ---------------------------------------------------------------------------
__global__ __launch_bounds__(256) void prep_qkv(
    const float* __restrict__ qkv, __bf16* __restrict__ Qg,
    __bf16* __restrict__ Kg, __bf16* __restrict__ Vt) {
  __shared__ __bf16 vt[64][136];
  const int bh = blockIdx.x;
  const int b = bh >> 3, h = bh & 7;
  const int sb = blockIdx.y * 128;
  const int tid = threadIdx.x;

  {
    const int row = tid >> 1, half = tid & 1;
    const size_t rb = ((size_t)b * 1024 + sb + row) * 1024;
    // q
    {
      const float* p = qkv + rb + h * 32 + half * 16;
      float4 a[4];
      float ss = 0.f;
#pragma unroll
      for (int i = 0; i < 4; ++i) {
        a[i] = ((const float4*)p)[i];
        ss += a[i].x * a[i].x + a[i].y * a[i].y + a[i].z * a[i].z + a[i].w * a[i].w;
      }
      ss += __shfl_xor(ss, 1, 64);
      float sc = 1.0f / fmaxf(sqrtf(ss), 1e-12f);
      float4 s0 = make_float4(a[0].x * sc, a[0].y * sc, a[0].z * sc, a[0].w * sc);
      float4 s1 = make_float4(a[1].x * sc, a[1].y * sc, a[1].z * sc, a[1].w * sc);
      float4 s2 = make_float4(a[2].x * sc, a[2].y * sc, a[2].z * sc, a[2].w * sc);
      float4 s3 = make_float4(a[3].x * sc, a[3].y * sc, a[3].z * sc, a[3].w * sc);
      uint4* o = (uint4*)(Qg + ((size_t)bh * 1024 + sb + row) * 32 + half * 16);
      o[0] = pack8(s0, s1);
      o[1] = pack8(s2, s3);
    }
    // k
    {
      const float* p = qkv + rb + 256 + h * 32 + half * 16;
      float4 a[4];
      float ss = 0.f;
#pragma unroll
      for (int i = 0; i < 4; ++i) {
        a[i] = ((const float4*)p)[i];
        ss += a[i].x * a[i].x + a[i].y * a[i].y + a[i].z * a[i].z + a[i].w * a[i].w;
      }
      ss += __shfl_xor(ss, 1, 64);
      float sc = 1.0f / fmaxf(sqrtf(ss), 1e-12f);
      float4 s0 = make_float4(a[0].x * sc, a[0].y * sc, a[0].z * sc, a[0].w * sc);
      float4 s1 = make_float4(a[1].x * sc, a[1].y * sc, a[1].z * sc, a[1].w * sc);
      float4 s2 = make_float4(a[2].x * sc, a[2].y * sc, a[2].z * sc, a[2].w * sc);
      float4 s3 = make_float4(a[3].x * sc, a[3].y * sc, a[3].z * sc, a[3].w * sc);
      uint4* o = (uint4*)(Kg + ((size_t)bh * 1024 + sb + row) * 32 + half * 16);
      o[0] = pack8(s0, s1);
      o[1] = pack8(s2, s3);
    }
  }

  // v transpose: read [t][vd] coalesced, LDS-scatter, write [vd][t]
#pragma unroll
  for (int i = 0; i < 8; ++i) {
    int idx = tid + i * 256;
    int t = idx >> 4, vd4 = (idx & 15) * 4;
    float4 v = *(const float4*)&qkv[((size_t)b * 1024 + sb + t) * 1024 + 512 + h * 64 + vd4];
    vt[vd4 + 0][t] = (__bf16)v.x;
    vt[vd4 + 1][t] = (__bf16)v.y;
    vt[vd4 + 2][t] = (__bf16)v.z;
    vt[vd4 + 3][t] = (__bf16)v.w;
  }
  __syncthreads();
  {
    const int vd = tid >> 2, tseg = (tid & 3) * 32;
    uint4* o = (uint4*)(Vt + (size_t)bh * 65536 + (size_t)vd * 1024 + sb + tseg);
#pragma unroll
    for (int j = 0; j < 4; ++j)
      o[j] = *(const uint4*)&vt[vd][tseg + j * 8];
  }
}

// ---------------------------------------------------------------------------
// MFMA causal attention (R4 structure; epilogue now writes bf16 y).
// ---------------------------------------------------------------------------
__global__ __launch_bounds__(256) void attn_mfma(
    const __bf16* __restrict__ Qg, const __bf16* __restrict__ Kg,
    const __bf16* __restrict__ Vt, const float* __restrict__ dist,
    const float* __restrict__ omega, __bf16* __restrict__ y) {
  __shared__ __bf16 Qs[64 * 32];
  __shared__ __bf16 Ks[64 * 32];
  __shared__ __bf16 Vs[64 * 64];
  __shared__ __bf16 zs[64][72];

  const int b = blockIdx.x;
  const int s0 = (15 - blockIdx.y) * 64;
  const int h = blockIdx.z;
  const int bh = b * 8 + h;
  const int tid = threadIdx.x;
  const int lane = tid & 63;
  const int w = tid >> 6;
  const int quad = lane >> 4;
  const int m = lane & 15;
  const float om = omega[h];
  const size_t rowbase = (size_t)b * SS;

  {
    int row = tid >> 2, p = tid & 3;
    uint4 v = *(const uint4*)(Qg + ((size_t)bh * 1024 + s0 + row) * 32 + p * 8);
    *(uint4*)&Qs[row * 32 + ((p ^ ((row >> 1) & 3)) * 8)] = v;
  }

  const int kswz = (quad ^ ((m >> 1) & 3)) * 8;
  const int sl = 16 * w + m;

  f32x4 acc[4];
#pragma unroll
  for (int ni = 0; ni < 4; ++ni) acc[ni] = (f32x4){0.f, 0.f, 0.f, 0.f};
  float zsum = 0.0f;
  const int ntiles = (s0 >> 6) + 1;

  for (int tt = 0; tt < ntiles; ++tt) {
    const int t0 = tt * 64;
    __syncthreads();
    {
      int row = tid >> 2, p = tid & 3;
      uint4 v = *(const uint4*)(Kg + ((size_t)bh * 1024 + t0 + row) * 32 + p * 8);
      *(uint4*)&Ks[row * 32 + ((p ^ ((row >> 1) & 3)) * 8)] = v;
    }
#pragma unroll
    for (int i = 0; i < 2; ++i) {
      int idx = tid + i * 256;
      int vd = idx >> 3, p = idx & 7;
      uint4 v = *(const uint4*)(Vt + (size_t)bh * 65536 + (size_t)vd * 1024 + t0 + p * 8);
      *(uint4*)&Vs[vd * 64 + ((p ^ (vd & 7)) * 8)] = v;
    }
    float4 dv[4];
#pragma unroll
    for (int mi = 0; mi < 4; ++mi)
      dv[mi] = *(const float4*)&dist[(rowbase + s0 + sl) * SS + t0 + 16 * mi + quad * 4];
    __syncthreads();

    const bf16x8 bq = *(const bf16x8*)&Qs[sl * 32 + kswz];
    f32x4 sc4[4];
#pragma unroll
    for (int mi = 0; mi < 4; ++mi) {
      const bf16x8 ak = *(const bf16x8*)&Ks[(16 * mi + m) * 32 + kswz];
      sc4[mi] = __builtin_amdgcn_mfma_f32_16x16x32_bf16(
          ak, bq, (f32x4){0.f, 0.f, 0.f, 0.f}, 0, 0, 0);
    }
    const bool diag = (tt == ntiles - 1);
#pragma unroll
    for (int mi = 0; mi < 4; ++mi) {
      float zr[4];
#pragma unroll
      for (int r = 0; r < 4; ++r) {
        float d = (&dv[mi].x)[r];
        float zv = __expf(sc4[mi][r] + __expf(-om * d) - 1.0f);
        if (diag && (16 * mi + quad * 4 + r) > sl) zv = 0.0f;
        zr[r] = zv;
        zsum += zv;
      }
      union { __hip_bfloat162 h2[2]; uint2 u; } pz;
      pz.h2[0] = __float22bfloat162_rn(make_float2(zr[0], zr[1]));
      pz.h2[1] = __float22bfloat162_rn(make_float2(zr[2], zr[3]));
      *(uint2*)&zs[sl][16 * mi + quad * 4] = pz.u;
    }
    __syncthreads();

    const bf16x8 za0 = *(const bf16x8*)&zs[sl][quad * 8];
    const bf16x8 za1 = *(const bf16x8*)&zs[sl][quad * 8 + 32];
#pragma unroll
    for (int ni = 0; ni < 4; ++ni) {
      const bf16x8 vb0 = *(const bf16x8*)&Vs[(16 * ni + m) * 64 + ((quad ^ (m & 7)) * 8)];
      const bf16x8 vb1 = *(const bf16x8*)&Vs[(16 * ni + m) * 64 + (((quad + 4) ^ (m & 7)) * 8)];
      acc[ni] = __builtin_amdgcn_mfma_f32_16x16x32_bf16(za0, vb0, acc[ni], 0, 0, 0);
      acc[ni] = __builtin_amdgcn_mfma_f32_16x16x32_bf16(za1, vb1, acc[ni], 0, 0, 0);
    }
  }

  zsum += __shfl_xor(zsum, 16, 64);
  zsum += __shfl_xor(zsum, 32, 64);

#pragma unroll
  for (int r = 0; r < 4; ++r) {
    float dn = __shfl(zsum, quad * 4 + r, 64);
    float inv = 1.0f / (dn + 1.0f);
    __bf16* yp = &y[(rowbase + s0 + 16 * w + quad * 4 + r) * 512 + h * 64 + m];
#pragma unroll
    for (int ni = 0; ni < 4; ++ni)
      yp[16 * ni] = (__bf16)(acc[ni][r] * inv);
  }
}

// ---------------------------------------------------------------------------
// Row-wise LayerNorm; optional bf16 secondary output (for GEMM A-operand).
// In-place safe (full row read before writes). One block per row.
// ---------------------------------------------------------------------------
__global__ __launch_bounds__(256) void ln_kernel(
    const float* __restrict__ in, const float* __restrict__ w,
    const float* __restrict__ bvec, float* __restrict__ out,
    __bf16* __restrict__ outb) {
  __shared__ float sbuf[4];
  const int m = blockIdx.x;
  const int tid = threadIdx.x;
  const float2 v = ((const float2*)(in + (size_t)m * 512))[tid];
  float s = v.x + v.y;
#pragma unroll
  for (int off = 32; off > 0; off >>= 1) s += __shfl_down(s, off, 64);
  const int lane = tid & 63, wid = tid >> 6;
  if (lane == 0) sbuf[wid] = s;
  __syncthreads();
  const float mu = (sbuf[0] + sbuf[1] + sbuf[2] + sbuf[3]) * (1.0f / 512.0f);
  __syncthreads();
  const float dx = v.x - mu, dy = v.y - mu;
  float s2 = dx * dx + dy * dy;
#pragma unroll
  for (int off = 32; off > 0; off >>= 1) s2 += __shfl_down(s2, off, 64);
  if (lane == 0) sbuf[wid] = s2;
  __syncthreads();
  const float var = (sbuf[0] + sbuf[1] + sbuf[2] + sbuf[3]) * (1.0f / 512.0f);
  const float inv = rsqrtf(var + 1e-5f);
  const float2 wv = ((const float2*)w)[tid];
  const float2 bv = ((const float2*)bvec)[tid];
  float2 o;
  o.x = dx * inv * wv.x + bv.x;
  o.y = dy * inv * wv.y + bv.y;
  ((float2*)(out + (size_t)m * 512))[tid] = o;
  if (outb) {
    union { __hip_bfloat162 h2; unsigned u; } p;
    p.h2 = __float22bfloat162_rn(make_float2(o.x, o.y));
    *(unsigned*)&outb[(size_t)m * 512 + tid * 2] = p.u;
  }
}

// ---------------------------------------------------------------------------
extern "C" void kernel_launch(void* const* d_in, const int* in_sizes, int n_in,
                              void* d_out, int out_size, void* d_ws, size_t ws_size,
                              hipStream_t stream) {
  const float* x = (const float*)d_in[0];
  // d_in[1] = attn_mask: deterministic causal triu(k=1) -> handled analytically
  const float* dist = (const float*)d_in[2];
  const float* Wq = (const float*)d_in[3];
  const float* Wk = (const float*)d_in[4];
  const float* Wv = (const float*)d_in[5];
  const float* omega = (const float*)d_in[6];
  const float* Wo = (const float*)d_in[7];
  const float* bo = (const float*)d_in[8];
  const float* Wf = (const float*)d_in[9];
  const float* bf_ = (const float*)d_in[10];
  const float* ln1w = (const float*)d_in[11];
  const float* ln1b = (const float*)d_in[12];
  const float* ln2w = (const float*)d_in[13];
  const float* ln2b = (const float*)d_in[14];
  float* out = (float*)d_out;

  // Workspace map (48 MB total), byte offsets; phases never overlap in time:
  //  [ 0,32M): qkv fp32 (gemm0 out)  ->  yb bf16 [0,8M) | t1 fp32 [8,24M) |
  //            t1b bf16 [24,32M)
  //  [32,48M): xb bf16 [32,40M) + Wcat [40,41M) (gemm0 phase)
  //         -> Qg [32,36M) | Kg [36,40M) | Vt [40,48M)   (attn phase)
  //         -> Wob [32,32.5M) | Wfb [32.5,33M)           (post-attn)
  //  h2 = d_out (gemm2 writes it, ln2 runs in-place)
  char* base = (char*)d_ws;
  const size_t MB = 1 << 20;
  float* qkv = (float*)base;
  __bf16* yb = (__bf16*)base;
  float* t1 = (float*)(base + 8 * MB);
  __bf16* t1b = (__bf16*)(base + 24 * MB);
  __bf16* xb = (__bf16*)(base + 32 * MB);
  __bf16* Wcat = (__bf16*)(base + 40 * MB);
  __bf16* Qg = (__bf16*)(base + 32 * MB);
  __bf16* Kg = (__bf16*)(base + 36 * MB);
  __bf16* Vt = (__bf16*)(base + 40 * MB);
  __bf16* Wob = (__bf16*)(base + 32 * MB);
  __bf16* Wfb = (__bf16*)(base + 32 * MB + 512 * 1024);

  dim3 blk(256);
  // 0a. x -> bf16 (4M elems)
  cvt_f32_bf16<<<dim3(2048), blk, 0, stream>>>(x, xb);
  // 0b. Wq|Wk|Wv -> Wcat bf16 (512K elems)
  cvt_wqkv<<<dim3(256), blk, 0, stream>>>(Wq, Wk, Wv, Wcat);
  // 1. QKV projection -> qkv fp32
  gemm_bf16<0><<<dim3(8, 64), blk, 0, stream>>>(xb, Wcat, nullptr, nullptr,
                                                qkv, 1024);
  // 2. prep: l2norm q,k -> Qg/Kg bf16; V -> Vt (bf16, transposed)
  prep_qkv<<<dim3(64, 8), blk, 0, stream>>>(qkv, Qg, Kg, Vt);
  // 3. MFMA causal attention -> yb (bf16, [b,s,h*64+vd])
  attn_mfma<<<dim3(8, 16, 8), blk, 0, stream>>>(Qg, Kg, Vt, dist, omega, yb);
  // 3b. Wo,Wf -> bf16 (Qg region is dead now)
  cvt_wof<<<dim3(256), blk, 0, stream>>>(Wo, Wf, Wob, Wfb);
  // 4. out-proj + bias + residual -> t1 fp32
  gemm_bf16<1><<<dim3(4, 64), blk, 0, stream>>>(yb, Wob, bo, x, t1, 512);
  // 5. LayerNorm1: t1 in-place (fp32) + t1b (bf16 A for FFN)
  ln_kernel<<<dim3(8192), blk, 0, stream>>>(t1, ln1w, ln1b, t1, t1b);
  // 6. FFN + leaky-relu + residual -> d_out (as h2 scratch)
  gemm_bf16<2><<<dim3(4, 64), blk, 0, stream>>>(t1b, Wfb, bf_, t1, out, 512);
  // 7. LayerNorm2 in-place on d_out
  ln_kernel<<<dim3(8192), blk, 0, stream>>>(out, ln2w, ln2b, out, nullptr);
}